// Round 4
// baseline (119.138 us; speedup 1.0000x reference)
//
#include <hip/hip_runtime.h>

// AnalyticalBoundedLineAttractor — exact linear-regime stepping via Taylor
// recurrence:
//   z = Wx + b; m_dt = (z>0)?dt:0
//   w1 = m_dt*z - dt*x;  wk = (m_dt*(W w) - dt*w)/k;  x+ = x + sum wk
// ||W||_2 ~ 2 (MP edge) -> ||Z|| <= dt*3 = 0.15; K=3 terms, measured absmax
// 0.0156 vs threshold 7.7e-2.
//
// Matvec: broadcast form, lane i holds row i of W in 64 VGPRs. R3 lesson:
// v_readlane (SGPR write) immediately consumed by v_fmac stalls on the
// VALU-writes-SGPR->VALU-reads-SGPR hazard (~2 cyc/pair, 520 cyc/matvec
// measured). Fix: gather 32 broadcast values into 32 independent SGPRs
// FIRST, then issue 32 v_fmac_f32 (SGPR is the one legal scalar operand),
// each >=32 instructions after its producer -> zero hazard stalls.
// Two 32-halves cap SGPR pressure at ~62 of 102 (no spill).

#define DT_F 0.05f
#define T_STEPS 100
#define DD 64
#define KT 3  // Taylor terms w_1..w_KT

__device__ __forceinline__ float matvec64(const float (&Wr)[DD], float w) {
    const int wi = __float_as_int(w);
    float a0 = 0.f, a1 = 0.f, a2 = 0.f, a3 = 0.f;

    // ---- half 1: gather j=0..31 into SGPRs, then 32 hazard-free FMAs ----
    int s[32];
#pragma unroll
    for (int j = 0; j < 32; ++j)
        s[j] = __builtin_amdgcn_readlane(wi, j);
#pragma unroll
    for (int j = 0; j < 32; j += 4) {
        a0 = fmaf(Wr[j + 0], __int_as_float(s[j + 0]), a0);
        a1 = fmaf(Wr[j + 1], __int_as_float(s[j + 1]), a1);
        a2 = fmaf(Wr[j + 2], __int_as_float(s[j + 2]), a2);
        a3 = fmaf(Wr[j + 3], __int_as_float(s[j + 3]), a3);
    }

    // ---- half 2: j=32..63 ----
    int s2[32];
#pragma unroll
    for (int j = 0; j < 32; ++j)
        s2[j] = __builtin_amdgcn_readlane(wi, 32 + j);
#pragma unroll
    for (int j = 0; j < 32; j += 4) {
        a0 = fmaf(Wr[32 + j + 0], __int_as_float(s2[j + 0]), a0);
        a1 = fmaf(Wr[32 + j + 1], __int_as_float(s2[j + 1]), a1);
        a2 = fmaf(Wr[32 + j + 2], __int_as_float(s2[j + 2]), a2);
        a3 = fmaf(Wr[32 + j + 3], __int_as_float(s2[j + 3]), a3);
    }
    return (a0 + a1) + (a2 + a3);
}

__global__ __launch_bounds__(64, 1)
void abla_kernel(const float* __restrict__ x0,
                 const float* __restrict__ W,
                 const float* __restrict__ bvec,
                 float* __restrict__ out) {
    const int batch = blockIdx.x;
    const int lane = threadIdx.x;

    // Lane i caches row i of W (natural order) in 64 VGPRs. One-time load.
    float Wr[DD];
#pragma unroll
    for (int j = 0; j < DD; j += 4) {
        const float4 w4 = *reinterpret_cast<const float4*>(W + lane * DD + j);
        Wr[j + 0] = w4.x; Wr[j + 1] = w4.y; Wr[j + 2] = w4.z; Wr[j + 3] = w4.w;
    }
    const float bi = bvec[lane];
    float x = x0[batch * DD + lane];
    float* outp = out + (size_t)batch * T_STEPS * DD + lane;

    for (int t = 0; t < T_STEPS; ++t) {
        // Trajectory stores the state BEFORE the update (store is off the
        // dependency chain — no read of it later).
        outp[(size_t)t * DD] = x;

        // term 1: z = Wx + b gives the regime mask
        const float z = matvec64(Wr, x) + bi;
        const float m_dt = (z > 0.f) ? DT_F : 0.f;
        float w = m_dt * z - DT_F * x;
        float y = x + w;

        // terms 2..KT
#pragma unroll
        for (int k = 2; k <= KT; ++k) {
            const float v = matvec64(Wr, w);
            w = (m_dt * v - DT_F * w) * (1.0f / (float)k);
            y += w;
        }
        x = y;
    }
}

extern "C" void kernel_launch(void* const* d_in, const int* in_sizes, int n_in,
                              void* d_out, int out_size, void* d_ws, size_t ws_size,
                              hipStream_t stream) {
    const float* x0 = (const float*)d_in[0];   // (256, 64) f32
    const float* W  = (const float*)d_in[1];   // (64, 64)  f32
    const float* b  = (const float*)d_in[2];   // (64,)     f32
    float* out = (float*)d_out;                // (256, 100, 64) f32

    const int batch = in_sizes[0] / DD;        // 256
    abla_kernel<<<batch, DD, 0, stream>>>(x0, W, b, out);
}